// Round 2
// baseline (1340.092 us; speedup 1.0000x reference)
//
#include <hip/hip_runtime.h>
#include <math.h>

// Problem constants (B=2, H=16, L=2048, D=128, fp32 in/out, int32 mask)
constexpr int Bc_ = 2;
constexpr int Hc_ = 16;
constexpr int Lc_ = 2048;
constexpr int Dc_ = 128;
constexpr int BR  = 64;   // Q rows per block (4 waves x 16)
constexpr int BC  = 32;   // K rows per tile
constexpr float SCALE = 0.08838834764831845f;  // 1/sqrt(128)
constexpr float NEGV  = -10000.0f;

typedef __attribute__((ext_vector_type(8))) short          bf16x8;  // MFMA A/B frag
typedef __attribute__((ext_vector_type(8))) unsigned short u16x8;
typedef __attribute__((ext_vector_type(4))) float          f32x4;   // MFMA C/D frag

// fp32 -> bf16 round-to-nearest-even
__device__ __forceinline__ unsigned short f2bf(float f) {
  unsigned u = __builtin_bit_cast(unsigned, f);
  return (unsigned short)((u + 0x7fffu + ((u >> 16) & 1u)) >> 16);
}

// Workgroup barrier that does NOT drain vmcnt (unlike __syncthreads, which
// emits s_waitcnt vmcnt(0) lgkmcnt(0)). LDS cross-wave visibility only needs
// lgkmcnt(0); leaving vmcnt outstanding lets register prefetch loads stay in
// flight across the barrier (AITER-style pipeline).
__device__ __forceinline__ void barrier_lgkm() {
  asm volatile("s_waitcnt lgkmcnt(0)\n\ts_barrier" ::: "memory");
}

constexpr int KS_STRIDE = 136;  // K tile rows (+8 pad)
constexpr int VT_STRIDE = 72;   // V^T rows (32 k + pad), 16B-aligned
constexpr int PS_STRIDE = 40;   // P staging rows

__global__ __launch_bounds__(256, 4) void attn_fwd(
    const float* __restrict__ Q, const float* __restrict__ K,
    const float* __restrict__ V, const int* __restrict__ Mask,
    float* __restrict__ Out) {
  const int qblk = blockIdx.x;
  const int bh   = blockIdx.y;
  const int tid  = threadIdx.x;
  const int w    = tid >> 6;
  const int lane = tid & 63;
  const int t16  = lane & 15;
  const int quad = lane >> 4;

  const float* Qg = Q    + (size_t)bh * Lc_ * Dc_;
  const float* Kg = K    + (size_t)bh * Lc_ * Dc_;
  const float* Vg = V    + (size_t)bh * Lc_ * Dc_;
  const int*   Mg = Mask + (size_t)bh * Lc_ * Lc_;
  float*       Og = Out  + (size_t)bh * Lc_ * Dc_;

  const int qr0 = qblk * BR + w * 16;

  __shared__ alignas(16) unsigned short Ks[BC * KS_STRIDE];
  __shared__ alignas(16) unsigned short Vt[Dc_ * VT_STRIDE];
  __shared__ alignas(16) unsigned short Ps[4 * 16 * PS_STRIDE];

  // ---- Q fragments (A-operand), loaded once, pre-scaled ----
  bf16x8 qf[4];
  {
    const float* qrow = Qg + (size_t)(qr0 + t16) * Dc_ + quad * 8;
#pragma unroll
    for (int s = 0; s < 4; ++s) {
      const f32x4 a = *(const f32x4*)(qrow + s * 32);
      const f32x4 b = *(const f32x4*)(qrow + s * 32 + 4);
      bf16x8 f;
      f[0] = (short)f2bf(a[0] * SCALE); f[1] = (short)f2bf(a[1] * SCALE);
      f[2] = (short)f2bf(a[2] * SCALE); f[3] = (short)f2bf(a[3] * SCALE);
      f[4] = (short)f2bf(b[0] * SCALE); f[5] = (short)f2bf(b[1] * SCALE);
      f[6] = (short)f2bf(b[2] * SCALE); f[7] = (short)f2bf(b[3] * SCALE);
      qf[s] = f;
    }
  }

  f32x4 acc[8];
#pragma unroll
  for (int i = 0; i < 8; ++i) acc[i] = (f32x4)0.0f;
  float mstate[4] = {-INFINITY, -INFINITY, -INFINITY, -INFINITY};
  float lstate[4] = {0.f, 0.f, 0.f, 0.f};

  // Staging thread mappings
  const int krow = tid >> 3;   // 0..31, 8 threads/row (coalesced 64B)
  const int kcg  = tid & 7;
  const int vrow = tid & 31;
  const int vcg  = tid >> 5;

  const float* kbase_g = Kg + (size_t)krow * Dc_ + kcg * 16;
  const float* vbase_g = Vg + (size_t)vrow * Dc_ + vcg * 16;
  const int*   mbase_g = Mg + (size_t)(qr0 + quad * 4) * Lc_ + t16;

  // Prefetch registers (tile t+1 loaded during tile t's compute)
  f32x4 kr[4], vr[4];
  int   mA[8], mB[8];

  // ---- preload tile 0 ----
  {
#pragma unroll
    for (int i = 0; i < 4; ++i) kr[i] = *(const f32x4*)(kbase_g + i * 4);
#pragma unroll
    for (int i = 0; i < 4; ++i) vr[i] = *(const f32x4*)(vbase_g + i * 4);
#pragma unroll
    for (int r = 0; r < 4; ++r) {
      mA[2 * r]     = mbase_g[(size_t)r * Lc_];
      mA[2 * r + 1] = mbase_g[(size_t)r * Lc_ + 16];
    }
  }

  auto body = [&](int kb, const int* mcur, int* mnext) {
    // ---- 1. stage current K/V regs -> LDS (bf16) ----
    {
      u16x8 p0, p1;
      p0[0]=f2bf(kr[0][0]); p0[1]=f2bf(kr[0][1]); p0[2]=f2bf(kr[0][2]); p0[3]=f2bf(kr[0][3]);
      p0[4]=f2bf(kr[1][0]); p0[5]=f2bf(kr[1][1]); p0[6]=f2bf(kr[1][2]); p0[7]=f2bf(kr[1][3]);
      p1[0]=f2bf(kr[2][0]); p1[1]=f2bf(kr[2][1]); p1[2]=f2bf(kr[2][2]); p1[3]=f2bf(kr[2][3]);
      p1[4]=f2bf(kr[3][0]); p1[5]=f2bf(kr[3][1]); p1[6]=f2bf(kr[3][2]); p1[7]=f2bf(kr[3][3]);
      *(u16x8*)&Ks[krow * KS_STRIDE + kcg * 16]     = p0;
      *(u16x8*)&Ks[krow * KS_STRIDE + kcg * 16 + 8] = p1;
    }
#pragma unroll
    for (int c4 = 0; c4 < 4; ++c4) {
      Vt[(vcg * 16 + c4 * 4 + 0) * VT_STRIDE + vrow] = f2bf(vr[c4][0]);
      Vt[(vcg * 16 + c4 * 4 + 1) * VT_STRIDE + vrow] = f2bf(vr[c4][1]);
      Vt[(vcg * 16 + c4 * 4 + 2) * VT_STRIDE + vrow] = f2bf(vr[c4][2]);
      Vt[(vcg * 16 + c4 * 4 + 3) * VT_STRIDE + vrow] = f2bf(vr[c4][3]);
    }

    // ---- 2. issue next-tile global loads (stay in flight across barrier) ----
    {
      int kbn = kb + BC;
      if (kbn >= Lc_) kbn = 0;  // harmless wrap on last iter
      const float* kp = kbase_g + (size_t)kbn * Dc_;
      const float* vp = vbase_g + (size_t)kbn * Dc_;
#pragma unroll
      for (int i = 0; i < 4; ++i) kr[i] = *(const f32x4*)(kp + i * 4);
#pragma unroll
      for (int i = 0; i < 4; ++i) vr[i] = *(const f32x4*)(vp + i * 4);
#pragma unroll
      for (int r = 0; r < 4; ++r) {
        mnext[2 * r]     = mbase_g[(size_t)r * Lc_ + kbn];
        mnext[2 * r + 1] = mbase_g[(size_t)r * Lc_ + kbn + 16];
      }
    }

    // ---- 3. barrier (lgkm only; vmem prefetch stays outstanding) ----
    barrier_lgkm();

    // ---- 4. S = (Q*scale) K^T ----
    f32x4 sblk[2];
#pragma unroll
    for (int blk = 0; blk < 2; ++blk) {
      f32x4 s = (f32x4)0.0f;
      const unsigned short* kb_l = &Ks[(blk * 16 + t16) * KS_STRIDE + quad * 8];
#pragma unroll
      for (int st = 0; st < 4; ++st) {
        bf16x8 bf = *(const bf16x8*)(kb_l + st * 32);
        s = __builtin_amdgcn_mfma_f32_16x16x32_bf16(qf[st], bf, s, 0, 0, 0);
      }
      sblk[blk] = s;
    }

    // ---- 5. mask + online softmax (mask already in registers) ----
#pragma unroll
    for (int r = 0; r < 4; ++r) {
      float s0 = (mcur[2 * r]     == 0) ? NEGV : sblk[0][r];
      float s1 = (mcur[2 * r + 1] == 0) ? NEGV : sblk[1][r];
      float rowmax = fmaxf(s0, s1);
      rowmax = fmaxf(rowmax, __shfl_xor(rowmax, 1));
      rowmax = fmaxf(rowmax, __shfl_xor(rowmax, 2));
      rowmax = fmaxf(rowmax, __shfl_xor(rowmax, 4));
      rowmax = fmaxf(rowmax, __shfl_xor(rowmax, 8));
      const float mnew  = fmaxf(mstate[r], rowmax);
      const float alpha = __expf(mstate[r] - mnew);
      const float p0 = __expf(s0 - mnew);
      const float p1 = __expf(s1 - mnew);
      float rs = p0 + p1;
      rs += __shfl_xor(rs, 1);
      rs += __shfl_xor(rs, 2);
      rs += __shfl_xor(rs, 4);
      rs += __shfl_xor(rs, 8);
      lstate[r] = lstate[r] * alpha + rs;
      mstate[r] = mnew;
#pragma unroll
      for (int nb = 0; nb < 8; ++nb) acc[nb][r] *= alpha;
      unsigned short* prow = &Ps[(w * 16 + quad * 4 + r) * PS_STRIDE];
      prow[t16]      = f2bf(p0);
      prow[16 + t16] = f2bf(p1);
    }

    // ---- O += P * V ----
    const bf16x8 pf = *(const bf16x8*)&Ps[(w * 16 + t16) * PS_STRIDE + quad * 8];
#pragma unroll
    for (int nb = 0; nb < 8; ++nb) {
      bf16x8 vf = *(const bf16x8*)&Vt[(nb * 16 + t16) * VT_STRIDE + quad * 8];
      acc[nb] = __builtin_amdgcn_mfma_f32_16x16x32_bf16(pf, vf, acc[nb], 0, 0, 0);
    }

    // ---- 6. protect LDS before next overwrite ----
    barrier_lgkm();
  };

#pragma unroll 1
  for (int kb = 0; kb < Lc_; kb += 2 * BC) {
    body(kb,      mA, mB);
    body(kb + BC, mB, mA);
  }

  // ---- epilogue: O / l ----
#pragma unroll
  for (int r = 0; r < 4; ++r) {
    const float inv = 1.0f / lstate[r];
    float* orow = Og + (size_t)(qr0 + quad * 4 + r) * Dc_ + t16;
#pragma unroll
    for (int nb = 0; nb < 8; ++nb) orow[nb * 16] = acc[nb][r] * inv;
  }
}

extern "C" void kernel_launch(void* const* d_in, const int* in_sizes, int n_in,
                              void* d_out, int out_size, void* d_ws, size_t ws_size,
                              hipStream_t stream) {
  const float* Q    = (const float*)d_in[0];
  const float* K    = (const float*)d_in[1];
  const float* V    = (const float*)d_in[2];
  const int*   Mask = (const int*)d_in[3];
  float*       Out  = (float*)d_out;
  dim3 grid(Lc_ / BR, Bc_ * Hc_);
  attn_fwd<<<grid, dim3(256), 0, stream>>>(Q, K, V, Mask, Out);
}

// Round 3
// 1255.797 us; speedup vs baseline: 1.0671x; 1.0671x over previous
//
#include <hip/hip_runtime.h>
#include <math.h>

// Problem constants (B=2, H=16, L=2048, D=128, fp32 in/out, int32 mask)
constexpr int Bc_ = 2;
constexpr int Hc_ = 16;
constexpr int Lc_ = 2048;
constexpr int Dc_ = 128;
constexpr int BR  = 64;   // Q rows per block (4 waves x 16)
constexpr int BC  = 32;   // K rows per tile
constexpr float SCALE = 0.08838834764831845f;  // 1/sqrt(128)
constexpr float NEGV  = -10000.0f;

typedef __attribute__((ext_vector_type(8))) short          bf16x8;
typedef __attribute__((ext_vector_type(8))) unsigned short u16x8;
typedef __attribute__((ext_vector_type(4))) float          f32x4;

// fp32 -> bf16 round-to-nearest-even
__device__ __forceinline__ unsigned short f2bf(float f) {
  unsigned u = __builtin_bit_cast(unsigned, f);
  return (unsigned short)((u + 0x7fffu + ((u >> 16) & 1u)) >> 16);
}

// Workgroup barrier that does NOT drain vmcnt (unlike __syncthreads).
// LDS visibility needs lgkmcnt(0) only; register-prefetch global loads
// stay in flight across the barrier.
__device__ __forceinline__ void barrier_lgkm() {
  asm volatile("s_waitcnt lgkmcnt(0)\n\ts_barrier" ::: "memory");
}

constexpr int KS_STRIDE = 136;  // K tile rows (+8 pad)
constexpr int VT_STRIDE = 72;   // V^T rows, 16B-aligned
constexpr int PS_STRIDE = 40;   // P staging rows

// ---- softmax for one Q-row R, masks as named scalar registers ----
#define SOFTMAX_ROW(R, M0, M1)                                              \
  {                                                                         \
    float s0 = ((M0) == 0) ? NEGV : sblk[0][R];                             \
    float s1 = ((M1) == 0) ? NEGV : sblk[1][R];                             \
    float rowmax = fmaxf(s0, s1);                                           \
    rowmax = fmaxf(rowmax, __shfl_xor(rowmax, 1));                          \
    rowmax = fmaxf(rowmax, __shfl_xor(rowmax, 2));                          \
    rowmax = fmaxf(rowmax, __shfl_xor(rowmax, 4));                          \
    rowmax = fmaxf(rowmax, __shfl_xor(rowmax, 8));                          \
    const float mnew  = fmaxf(mstate[R], rowmax);                           \
    const float alpha = __expf(mstate[R] - mnew);                           \
    const float p0 = __expf(s0 - mnew);                                     \
    const float p1 = __expf(s1 - mnew);                                     \
    float rs = p0 + p1;                                                     \
    rs += __shfl_xor(rs, 1);                                                \
    rs += __shfl_xor(rs, 2);                                                \
    rs += __shfl_xor(rs, 4);                                                \
    rs += __shfl_xor(rs, 8);                                                \
    lstate[R] = lstate[R] * alpha + rs;                                     \
    mstate[R] = mnew;                                                       \
    acc[0][R] *= alpha; acc[1][R] *= alpha; acc[2][R] *= alpha;             \
    acc[3][R] *= alpha; acc[4][R] *= alpha; acc[5][R] *= alpha;             \
    acc[6][R] *= alpha; acc[7][R] *= alpha;                                 \
    unsigned short* prow = &Ps[(w * 16 + quad * 4 + (R)) * PS_STRIDE];      \
    prow[t16]      = f2bf(p0);                                              \
    prow[16 + t16] = f2bf(p1);                                              \
  }

// ---- one K-tile iteration. MC*/MN* are named scalar mask registers. ----
#define TILE_BODY(KB, MC, MN)                                               \
  {                                                                         \
    /* 1. stage current K regs -> LDS (bf16, row-major) */                  \
    {                                                                       \
      u16x8 p0, p1;                                                         \
      p0[0]=f2bf(kr[0][0]); p0[1]=f2bf(kr[0][1]); p0[2]=f2bf(kr[0][2]); p0[3]=f2bf(kr[0][3]); \
      p0[4]=f2bf(kr[1][0]); p0[5]=f2bf(kr[1][1]); p0[6]=f2bf(kr[1][2]); p0[7]=f2bf(kr[1][3]); \
      p1[0]=f2bf(kr[2][0]); p1[1]=f2bf(kr[2][1]); p1[2]=f2bf(kr[2][2]); p1[3]=f2bf(kr[2][3]); \
      p1[4]=f2bf(kr[3][0]); p1[5]=f2bf(kr[3][1]); p1[6]=f2bf(kr[3][2]); p1[7]=f2bf(kr[3][3]); \
      *(u16x8*)&Ks[krow * KS_STRIDE + kcg * 16]     = p0;                   \
      *(u16x8*)&Ks[krow * KS_STRIDE + kcg * 16 + 8] = p1;                   \
    }                                                                       \
    /* stage current V regs -> LDS transposed */                            \
    _Pragma("unroll")                                                       \
    for (int c4 = 0; c4 < 4; ++c4) {                                        \
      Vt[(vcg * 16 + c4 * 4 + 0) * VT_STRIDE + vrow] = f2bf(vr[c4][0]);     \
      Vt[(vcg * 16 + c4 * 4 + 1) * VT_STRIDE + vrow] = f2bf(vr[c4][1]);     \
      Vt[(vcg * 16 + c4 * 4 + 2) * VT_STRIDE + vrow] = f2bf(vr[c4][2]);     \
      Vt[(vcg * 16 + c4 * 4 + 3) * VT_STRIDE + vrow] = f2bf(vr[c4][3]);     \
    }                                                                       \
    /* 2. issue next-tile global loads (stay in flight across barrier) */   \
    {                                                                       \
      int kbn = (KB) + BC;                                                  \
      if (kbn >= Lc_) kbn = 0;                                              \
      const float* kp = kbase_g + (size_t)kbn * Dc_;                        \
      const float* vp = vbase_g + (size_t)kbn * Dc_;                        \
      kr[0] = *(const f32x4*)(kp + 0);  kr[1] = *(const f32x4*)(kp + 4);    \
      kr[2] = *(const f32x4*)(kp + 8);  kr[3] = *(const f32x4*)(kp + 12);   \
      vr[0] = *(const f32x4*)(vp + 0);  vr[1] = *(const f32x4*)(vp + 4);    \
      vr[2] = *(const f32x4*)(vp + 8);  vr[3] = *(const f32x4*)(vp + 12);   \
      const int* mp = mbase_g + kbn;                                        \
      MN##0 = mp[0 * Lc_];      MN##1 = mp[0 * Lc_ + 16];                   \
      MN##2 = mp[1 * Lc_];      MN##3 = mp[1 * Lc_ + 16];                   \
      MN##4 = mp[2 * Lc_];      MN##5 = mp[2 * Lc_ + 16];                   \
      MN##6 = mp[3 * Lc_];      MN##7 = mp[3 * Lc_ + 16];                   \
    }                                                                       \
    /* 3. barrier (lgkm only) */                                            \
    barrier_lgkm();                                                         \
    /* 4. S = (Q*scale) K^T */                                              \
    f32x4 sblk[2];                                                          \
    _Pragma("unroll")                                                       \
    for (int blk = 0; blk < 2; ++blk) {                                     \
      f32x4 s = (f32x4)0.0f;                                                \
      const unsigned short* kb_l = &Ks[(blk * 16 + t16) * KS_STRIDE + quad * 8]; \
      _Pragma("unroll")                                                     \
      for (int st = 0; st < 4; ++st) {                                      \
        bf16x8 bf = *(const bf16x8*)(kb_l + st * 32);                       \
        s = __builtin_amdgcn_mfma_f32_16x16x32_bf16(qf[st], bf, s, 0, 0, 0);\
      }                                                                     \
      sblk[blk] = s;                                                        \
    }                                                                       \
    /* 5. mask + online softmax (masks already in registers) */             \
    SOFTMAX_ROW(0, MC##0, MC##1)                                            \
    SOFTMAX_ROW(1, MC##2, MC##3)                                            \
    SOFTMAX_ROW(2, MC##4, MC##5)                                            \
    SOFTMAX_ROW(3, MC##6, MC##7)                                            \
    /* 6. O += P * V */                                                     \
    {                                                                       \
      const bf16x8 pf = *(const bf16x8*)&Ps[(w * 16 + t16) * PS_STRIDE + quad * 8]; \
      _Pragma("unroll")                                                     \
      for (int nb = 0; nb < 8; ++nb) {                                      \
        bf16x8 vf = *(const bf16x8*)&Vt[(nb * 16 + t16) * VT_STRIDE + quad * 8]; \
        acc[nb] = __builtin_amdgcn_mfma_f32_16x16x32_bf16(pf, vf, acc[nb], 0, 0, 0); \
      }                                                                     \
    }                                                                       \
    /* 7. protect LDS before next overwrite */                              \
    barrier_lgkm();                                                         \
  }

__global__ __launch_bounds__(256, 4) void attn_fwd(
    const float* __restrict__ Q, const float* __restrict__ K,
    const float* __restrict__ V, const int* __restrict__ Mask,
    float* __restrict__ Out) {
  const int qblk = blockIdx.x;
  const int bh   = blockIdx.y;
  const int tid  = threadIdx.x;
  const int w    = tid >> 6;
  const int lane = tid & 63;
  const int t16  = lane & 15;
  const int quad = lane >> 4;

  const float* Qg = Q    + (size_t)bh * Lc_ * Dc_;
  const float* Kg = K    + (size_t)bh * Lc_ * Dc_;
  const float* Vg = V    + (size_t)bh * Lc_ * Dc_;
  const int*   Mg = Mask + (size_t)bh * Lc_ * Lc_;
  float*       Og = Out  + (size_t)bh * Lc_ * Dc_;

  const int qr0 = qblk * BR + w * 16;

  __shared__ alignas(16) unsigned short Ks[BC * KS_STRIDE];
  __shared__ alignas(16) unsigned short Vt[Dc_ * VT_STRIDE];
  __shared__ alignas(16) unsigned short Ps[4 * 16 * PS_STRIDE];

  // ---- Q fragments (A-operand), loaded once, pre-scaled ----
  bf16x8 qf[4];
  {
    const float* qrow = Qg + (size_t)(qr0 + t16) * Dc_ + quad * 8;
#pragma unroll
    for (int s = 0; s < 4; ++s) {
      const f32x4 a = *(const f32x4*)(qrow + s * 32);
      const f32x4 b = *(const f32x4*)(qrow + s * 32 + 4);
      bf16x8 f;
      f[0] = (short)f2bf(a[0] * SCALE); f[1] = (short)f2bf(a[1] * SCALE);
      f[2] = (short)f2bf(a[2] * SCALE); f[3] = (short)f2bf(a[3] * SCALE);
      f[4] = (short)f2bf(b[0] * SCALE); f[5] = (short)f2bf(b[1] * SCALE);
      f[6] = (short)f2bf(b[2] * SCALE); f[7] = (short)f2bf(b[3] * SCALE);
      qf[s] = f;
    }
  }

  f32x4 acc[8];
#pragma unroll
  for (int i = 0; i < 8; ++i) acc[i] = (f32x4)0.0f;
  float mstate[4] = {-INFINITY, -INFINITY, -INFINITY, -INFINITY};
  float lstate[4] = {0.f, 0.f, 0.f, 0.f};

  // Staging thread mappings
  const int krow = tid >> 3;   // 0..31, 8 threads/row (coalesced 64B)
  const int kcg  = tid & 7;
  const int vrow = tid & 31;
  const int vcg  = tid >> 5;

  const float* kbase_g = Kg + (size_t)krow * Dc_ + kcg * 16;
  const float* vbase_g = Vg + (size_t)vrow * Dc_ + vcg * 16;
  const int*   mbase_g = Mg + (size_t)(qr0 + quad * 4) * Lc_ + t16;

  // Prefetch registers: K/V tiles as f32x4, masks as NAMED SCALARS
  // (runtime-pointer-indexed arrays go to scratch -> 1.8 GB HBM spill, R2)
  f32x4 kr[4], vr[4];
  int mA0, mA1, mA2, mA3, mA4, mA5, mA6, mA7;
  int mB0, mB1, mB2, mB3, mB4, mB5, mB6, mB7;

  // ---- preload tile 0 ----
  kr[0] = *(const f32x4*)(kbase_g + 0);  kr[1] = *(const f32x4*)(kbase_g + 4);
  kr[2] = *(const f32x4*)(kbase_g + 8);  kr[3] = *(const f32x4*)(kbase_g + 12);
  vr[0] = *(const f32x4*)(vbase_g + 0);  vr[1] = *(const f32x4*)(vbase_g + 4);
  vr[2] = *(const f32x4*)(vbase_g + 8);  vr[3] = *(const f32x4*)(vbase_g + 12);
  mA0 = mbase_g[0 * Lc_];  mA1 = mbase_g[0 * Lc_ + 16];
  mA2 = mbase_g[1 * Lc_];  mA3 = mbase_g[1 * Lc_ + 16];
  mA4 = mbase_g[2 * Lc_];  mA5 = mbase_g[2 * Lc_ + 16];
  mA6 = mbase_g[3 * Lc_];  mA7 = mbase_g[3 * Lc_ + 16];

#pragma unroll 1
  for (int kb = 0; kb < Lc_; kb += 2 * BC) {
    TILE_BODY(kb,      mA, mB)
    TILE_BODY(kb + BC, mB, mA)
  }

  // ---- epilogue: O / l ----
#pragma unroll
  for (int r = 0; r < 4; ++r) {
    const float inv = 1.0f / lstate[r];
    float* orow = Og + (size_t)(qr0 + quad * 4 + r) * Dc_ + t16;
#pragma unroll
    for (int nb = 0; nb < 8; ++nb) orow[nb * 16] = acc[nb][r] * inv;
  }
}

extern "C" void kernel_launch(void* const* d_in, const int* in_sizes, int n_in,
                              void* d_out, int out_size, void* d_ws, size_t ws_size,
                              hipStream_t stream) {
  const float* Q    = (const float*)d_in[0];
  const float* K    = (const float*)d_in[1];
  const float* V    = (const float*)d_in[2];
  const int*   Mask = (const int*)d_in[3];
  float*       Out  = (float*)d_out;
  dim3 grid(Lc_ / BR, Bc_ * Hc_);
  attn_fwd<<<grid, dim3(256), 0, stream>>>(Q, K, V, Mask, Out);
}

// Round 4
// 920.670 us; speedup vs baseline: 1.4556x; 1.3640x over previous
//
#include <hip/hip_runtime.h>
#include <math.h>

// Problem constants (B=2, H=16, L=2048, D=128, fp32 in/out, int32 mask)
constexpr int Bc_ = 2;
constexpr int Hc_ = 16;
constexpr int Lc_ = 2048;
constexpr int Dc_ = 128;
constexpr int BR  = 64;   // Q rows per block (4 waves x 16)
constexpr int BC  = 32;   // K rows per tile
constexpr float SCALE = 0.08838834764831845f;  // 1/sqrt(128)
constexpr float NEGV  = -10000.0f;

typedef __attribute__((ext_vector_type(8))) short          bf16x8;
typedef __attribute__((ext_vector_type(8))) unsigned short u16x8;
typedef __attribute__((ext_vector_type(4))) float          f32x4;

// fp32 -> bf16 round-to-nearest-even
__device__ __forceinline__ unsigned short f2bf(float f) {
  unsigned u = __builtin_bit_cast(unsigned, f);
  return (unsigned short)((u + 0x7fffu + ((u >> 16) & 1u)) >> 16);
}

// Workgroup barrier that does NOT drain vmcnt (unlike __syncthreads).
// LDS visibility needs lgkmcnt(0) only; register-prefetch global loads
// stay in flight across the barrier.
__device__ __forceinline__ void barrier_lgkm() {
  asm volatile("s_waitcnt lgkmcnt(0)\n\ts_barrier" ::: "memory");
}

constexpr int KS_STRIDE = 136;  // K tile rows (+8 pad)
constexpr int VT_STRIDE = 72;   // V^T rows, 16B-aligned
constexpr int PS_STRIDE = 40;   // P staging rows

// ---- softmax for one Q-row R, masks as named scalar registers ----
#define SOFTMAX_ROW(R, M0, M1)                                              \
  {                                                                         \
    float s0 = ((M0) == 0) ? NEGV : sblk[0][R];                             \
    float s1 = ((M1) == 0) ? NEGV : sblk[1][R];                             \
    float rowmax = fmaxf(s0, s1);                                           \
    rowmax = fmaxf(rowmax, __shfl_xor(rowmax, 1));                          \
    rowmax = fmaxf(rowmax, __shfl_xor(rowmax, 2));                          \
    rowmax = fmaxf(rowmax, __shfl_xor(rowmax, 4));                          \
    rowmax = fmaxf(rowmax, __shfl_xor(rowmax, 8));                          \
    const float mnew  = fmaxf(mstate[R], rowmax);                           \
    const float alpha = __expf(mstate[R] - mnew);                           \
    const float p0 = __expf(s0 - mnew);                                     \
    const float p1 = __expf(s1 - mnew);                                     \
    float rs = p0 + p1;                                                     \
    rs += __shfl_xor(rs, 1);                                                \
    rs += __shfl_xor(rs, 2);                                                \
    rs += __shfl_xor(rs, 4);                                                \
    rs += __shfl_xor(rs, 8);                                                \
    lstate[R] = lstate[R] * alpha + rs;                                     \
    mstate[R] = mnew;                                                       \
    acc[0][R] *= alpha; acc[1][R] *= alpha; acc[2][R] *= alpha;             \
    acc[3][R] *= alpha; acc[4][R] *= alpha; acc[5][R] *= alpha;             \
    acc[6][R] *= alpha; acc[7][R] *= alpha;                                 \
    unsigned short* prow = &Ps[(w * 16 + quad * 4 + (R)) * PS_STRIDE];      \
    prow[t16]      = f2bf(p0);                                              \
    prow[16 + t16] = f2bf(p1);                                              \
  }

// ---- one K-tile iteration. MC*/MN* are named scalar mask registers. ----
#define TILE_BODY(KB, MC, MN)                                               \
  {                                                                         \
    /* 1. stage current K regs -> LDS (bf16, row-major) */                  \
    {                                                                       \
      u16x8 p0, p1;                                                         \
      p0[0]=f2bf(kr[0][0]); p0[1]=f2bf(kr[0][1]); p0[2]=f2bf(kr[0][2]); p0[3]=f2bf(kr[0][3]); \
      p0[4]=f2bf(kr[1][0]); p0[5]=f2bf(kr[1][1]); p0[6]=f2bf(kr[1][2]); p0[7]=f2bf(kr[1][3]); \
      p1[0]=f2bf(kr[2][0]); p1[1]=f2bf(kr[2][1]); p1[2]=f2bf(kr[2][2]); p1[3]=f2bf(kr[2][3]); \
      p1[4]=f2bf(kr[3][0]); p1[5]=f2bf(kr[3][1]); p1[6]=f2bf(kr[3][2]); p1[7]=f2bf(kr[3][3]); \
      *(u16x8*)&Ks[krow * KS_STRIDE + kcg * 16]     = p0;                   \
      *(u16x8*)&Ks[krow * KS_STRIDE + kcg * 16 + 8] = p1;                   \
    }                                                                       \
    /* stage current V regs -> LDS transposed */                            \
    _Pragma("unroll")                                                       \
    for (int c4 = 0; c4 < 4; ++c4) {                                        \
      Vt[(vcg * 16 + c4 * 4 + 0) * VT_STRIDE + vrow] = f2bf(vr[c4][0]);     \
      Vt[(vcg * 16 + c4 * 4 + 1) * VT_STRIDE + vrow] = f2bf(vr[c4][1]);     \
      Vt[(vcg * 16 + c4 * 4 + 2) * VT_STRIDE + vrow] = f2bf(vr[c4][2]);     \
      Vt[(vcg * 16 + c4 * 4 + 3) * VT_STRIDE + vrow] = f2bf(vr[c4][3]);     \
    }                                                                       \
    /* 2. issue next-tile global loads (stay in flight across barrier) */   \
    {                                                                       \
      const int kbn = ((KB) + BC) & (Lc_ - 1);                              \
      const float* kp = kbase_g + (size_t)kbn * Dc_;                        \
      const float* vp = vbase_g + (size_t)kbn * Dc_;                        \
      kr[0] = *(const f32x4*)(kp + 0);  kr[1] = *(const f32x4*)(kp + 4);    \
      kr[2] = *(const f32x4*)(kp + 8);  kr[3] = *(const f32x4*)(kp + 12);   \
      vr[0] = *(const f32x4*)(vp + 0);  vr[1] = *(const f32x4*)(vp + 4);    \
      vr[2] = *(const f32x4*)(vp + 8);  vr[3] = *(const f32x4*)(vp + 12);   \
      const int* mp = mbase_g + kbn;                                        \
      MN##0 = mp[0 * Lc_];      MN##1 = mp[0 * Lc_ + 16];                   \
      MN##2 = mp[1 * Lc_];      MN##3 = mp[1 * Lc_ + 16];                   \
      MN##4 = mp[2 * Lc_];      MN##5 = mp[2 * Lc_ + 16];                   \
      MN##6 = mp[3 * Lc_];      MN##7 = mp[3 * Lc_ + 16];                   \
    }                                                                       \
    /* 3. barrier (lgkm only) */                                            \
    barrier_lgkm();                                                         \
    /* 4. S = (Q*scale) K^T */                                              \
    f32x4 sblk[2];                                                          \
    _Pragma("unroll")                                                       \
    for (int blk = 0; blk < 2; ++blk) {                                     \
      f32x4 s = (f32x4)0.0f;                                                \
      const unsigned short* kb_l = &Ks[(blk * 16 + t16) * KS_STRIDE + quad * 8]; \
      _Pragma("unroll")                                                     \
      for (int st = 0; st < 4; ++st) {                                      \
        bf16x8 bf = *(const bf16x8*)(kb_l + st * 32);                       \
        s = __builtin_amdgcn_mfma_f32_16x16x32_bf16(qf[st], bf, s, 0, 0, 0);\
      }                                                                     \
      sblk[blk] = s;                                                        \
    }                                                                       \
    /* 5. mask + online softmax (masks already in registers) */             \
    SOFTMAX_ROW(0, MC##0, MC##1)                                            \
    SOFTMAX_ROW(1, MC##2, MC##3)                                            \
    SOFTMAX_ROW(2, MC##4, MC##5)                                            \
    SOFTMAX_ROW(3, MC##6, MC##7)                                            \
    /* 6. O += P * V */                                                     \
    {                                                                       \
      const bf16x8 pf = *(const bf16x8*)&Ps[(w * 16 + t16) * PS_STRIDE + quad * 8]; \
      _Pragma("unroll")                                                     \
      for (int nb = 0; nb < 8; ++nb) {                                      \
        bf16x8 vf = *(const bf16x8*)&Vt[(nb * 16 + t16) * VT_STRIDE + quad * 8]; \
        acc[nb] = __builtin_amdgcn_mfma_f32_16x16x32_bf16(pf, vf, acc[nb], 0, 0, 0); \
      }                                                                     \
    }                                                                       \
    /* 7. protect LDS before next overwrite */                              \
    barrier_lgkm();                                                         \
  }

// launch_bounds(256, 3): VGPR cap ~170 — the pipeline needs ~140 live regs.
// (256, 4) capped at 64 and spilled ~1.6 GB/dispatch to scratch (R2/R3).
__global__ __launch_bounds__(256, 3) void attn_fwd(
    const float* __restrict__ Q, const float* __restrict__ K,
    const float* __restrict__ V, const int* __restrict__ Mask,
    float* __restrict__ Out) {
  const int qblk = blockIdx.x;
  const int bh   = blockIdx.y;
  const int tid  = threadIdx.x;
  const int w    = tid >> 6;
  const int lane = tid & 63;
  const int t16  = lane & 15;
  const int quad = lane >> 4;

  const float* Qg = Q    + (size_t)bh * Lc_ * Dc_;
  const float* Kg = K    + (size_t)bh * Lc_ * Dc_;
  const float* Vg = V    + (size_t)bh * Lc_ * Dc_;
  const int*   Mg = Mask + (size_t)bh * Lc_ * Lc_;
  float*       Og = Out  + (size_t)bh * Lc_ * Dc_;

  const int qr0 = qblk * BR + w * 16;

  __shared__ alignas(16) unsigned short Ks[BC * KS_STRIDE];
  __shared__ alignas(16) unsigned short Vt[Dc_ * VT_STRIDE];
  __shared__ alignas(16) unsigned short Ps[4 * 16 * PS_STRIDE];

  // ---- Q fragments (A-operand), loaded once, pre-scaled ----
  bf16x8 qf[4];
  {
    const float* qrow = Qg + (size_t)(qr0 + t16) * Dc_ + quad * 8;
#pragma unroll
    for (int s = 0; s < 4; ++s) {
      const f32x4 a = *(const f32x4*)(qrow + s * 32);
      const f32x4 b = *(const f32x4*)(qrow + s * 32 + 4);
      bf16x8 f;
      f[0] = (short)f2bf(a[0] * SCALE); f[1] = (short)f2bf(a[1] * SCALE);
      f[2] = (short)f2bf(a[2] * SCALE); f[3] = (short)f2bf(a[3] * SCALE);
      f[4] = (short)f2bf(b[0] * SCALE); f[5] = (short)f2bf(b[1] * SCALE);
      f[6] = (short)f2bf(b[2] * SCALE); f[7] = (short)f2bf(b[3] * SCALE);
      qf[s] = f;
    }
  }

  f32x4 acc[8];
#pragma unroll
  for (int i = 0; i < 8; ++i) acc[i] = (f32x4)0.0f;
  float mstate[4] = {-INFINITY, -INFINITY, -INFINITY, -INFINITY};
  float lstate[4] = {0.f, 0.f, 0.f, 0.f};

  // Staging thread mappings
  const int krow = tid >> 3;   // 0..31, 8 threads/row (coalesced 64B)
  const int kcg  = tid & 7;
  const int vrow = tid & 31;
  const int vcg  = tid >> 5;

  const float* kbase_g = Kg + (size_t)krow * Dc_ + kcg * 16;
  const float* vbase_g = Vg + (size_t)vrow * Dc_ + vcg * 16;
  const int*   mbase_g = Mg + (size_t)(qr0 + quad * 4) * Lc_ + t16;

  // Prefetch registers: K/V tiles as f32x4, masks as NAMED SCALARS
  // (runtime-pointer-indexed arrays go to scratch -> 1.8 GB HBM spill, R2)
  f32x4 kr[4], vr[4];
  int mA0, mA1, mA2, mA3, mA4, mA5, mA6, mA7;
  int mB0, mB1, mB2, mB3, mB4, mB5, mB6, mB7;

  // ---- preload tile 0 ----
  kr[0] = *(const f32x4*)(kbase_g + 0);  kr[1] = *(const f32x4*)(kbase_g + 4);
  kr[2] = *(const f32x4*)(kbase_g + 8);  kr[3] = *(const f32x4*)(kbase_g + 12);
  vr[0] = *(const f32x4*)(vbase_g + 0);  vr[1] = *(const f32x4*)(vbase_g + 4);
  vr[2] = *(const f32x4*)(vbase_g + 8);  vr[3] = *(const f32x4*)(vbase_g + 12);
  mA0 = mbase_g[0 * Lc_];  mA1 = mbase_g[0 * Lc_ + 16];
  mA2 = mbase_g[1 * Lc_];  mA3 = mbase_g[1 * Lc_ + 16];
  mA4 = mbase_g[2 * Lc_];  mA5 = mbase_g[2 * Lc_ + 16];
  mA6 = mbase_g[3 * Lc_];  mA7 = mbase_g[3 * Lc_ + 16];

#pragma unroll 1
  for (int kb = 0; kb < Lc_; kb += 2 * BC) {
    TILE_BODY(kb,      mA, mB)
    TILE_BODY(kb + BC, mB, mA)
  }

  // ---- epilogue: O / l ----
#pragma unroll
  for (int r = 0; r < 4; ++r) {
    const float inv = 1.0f / lstate[r];
    float* orow = Og + (size_t)(qr0 + quad * 4 + r) * Dc_ + t16;
#pragma unroll
    for (int nb = 0; nb < 8; ++nb) orow[nb * 16] = acc[nb][r] * inv;
  }
}

extern "C" void kernel_launch(void* const* d_in, const int* in_sizes, int n_in,
                              void* d_out, int out_size, void* d_ws, size_t ws_size,
                              hipStream_t stream) {
  const float* Q    = (const float*)d_in[0];
  const float* K    = (const float*)d_in[1];
  const float* V    = (const float*)d_in[2];
  const int*   Mask = (const int*)d_in[3];
  float*       Out  = (float*)d_out;
  dim3 grid(Lc_ / BR, Bc_ * Hc_);
  attn_fwd<<<grid, dim3(256), 0, stream>>>(Q, K, V, Mask, Out);
}